// Round 1
// baseline (1431.287 us; speedup 1.0000x reference)
//
#include <hip/hip_runtime.h>
#include <math.h>

// Problem constants
#define B 16
#define T 12
#define HIN 48
#define WIN 48
#define CINX 3
#define NF 32          // filters per gate
#define H1 47
#define W1D 46
#define H2 46
#define W2D 44
#define PH 23
#define PW 22

__device__ __forceinline__ float hsig(float z) {
    return fminf(fmaxf(0.2f * z + 0.5f, 0.f), 1.f);
}

// ---------------------------------------------------------------------------
// Weight re-layout: dst[((ci*6 + kk)*32 + f)*4 + g] = src[(kk*CIN + ci)*128 + g*32 + f]
// (gate-fastest so one float4 load serves all 4 gates of channel f)
// ---------------------------------------------------------------------------
__global__ __launch_bounds__(256) void transform_weights(
    const float* __restrict__ W1s, const float* __restrict__ U1s,
    const float* __restrict__ W2s, const float* __restrict__ U2s,
    float* __restrict__ Wt1, float* __restrict__ Ut1,
    float* __restrict__ Wt2, float* __restrict__ Ut2)
{
    int idx = blockIdx.x * 256 + threadIdx.x;   // 0 .. 76031
    const float* src; float* dst; int cin; int off;
    if (idx < 2304)               { src = W1s; dst = Wt1; cin = 3;  off = idx; }
    else if (idx < 2304 + 24576)  { src = U1s; dst = Ut1; cin = 32; off = idx - 2304; }
    else if (idx < 2304 + 49152)  { src = W2s; dst = Wt2; cin = 32; off = idx - 2304 - 24576; }
    else                          { src = U2s; dst = Ut2; cin = 32; off = idx - 2304 - 49152; }
    int g = off & 3;
    int f = (off >> 2) & 31;
    int r = off >> 7;          // ci*6 + kk
    int kk = r % 6;
    int ci = r / 6;
    dst[off] = src[(kk * cin + ci) * 128 + g * 32 + f];
}

// ---------------------------------------------------------------------------
// One ConvLSTM timestep.
//   input conv : VALID, kernel 2x3, CIN channels, input spatial Hin x Win
//   recur conv : SAME  (pad H:(0,1), W:(1,1)), kernel 2x3, 32 channels, on Ho x Wo
// Block: 256 thr = (f 0..31) x (xq 0..3) x (yr 0..1); thread computes 4 x-positions.
// Block tile: 2 rows x 16 cols of output.
// ---------------------------------------------------------------------------
template <int CIN>
__global__ __launch_bounds__(256) void lstm_step(
    const float* __restrict__ xin, int xin_bstride, int Hin, int Win,
    const float* __restrict__ hprev,
    const float* __restrict__ Wt,   // [ci][kk][f][g], CIN channels
    const float* __restrict__ Ut,   // [ci][kk][f][g], 32 channels
    const float* __restrict__ bias, // [128]
    float* __restrict__ cst,        // [B,Ho,Wo,32] in/out
    float* __restrict__ hnext,      // [B,Ho,Wo,32]
    int Ho, int Wo)
{
    const int f  = threadIdx.x & 31;
    const int xi = threadIdx.x >> 5;   // 0..7
    const int xq = xi & 3;
    const int yr = xi >> 2;            // 0..1
    const int b  = blockIdx.z;
    const int y0 = blockIdx.y * 2;
    const int x0 = blockIdx.x * 16;
    const int y  = y0 + yr;
    const int cb = xq * 4;             // col base within tile

    __shared__ float pin[3 * CIN * 20]; // rows y0..y0+2, cols x0..x0+17 (pad->20)
    __shared__ float prc[3 * 32 * 20];  // rows y0..y0+2, cols x0-1..x0+16 (pad->20)

    // ---- stage input patch (valid conv source) ----
    for (int i = threadIdx.x; i < 3 * CIN * 20; i += 256) {
        int row = i / (CIN * 20);
        int r2  = i % (CIN * 20);
        int ci  = r2 / 20;
        int col = r2 % 20;
        int gy = y0 + row, gx = x0 + col;
        float v = 0.f;
        if (col < 18 && gy < Hin && gx < Win)
            v = xin[(size_t)b * xin_bstride + ((size_t)gy * Win + gx) * CIN + ci];
        pin[(row * CIN + ci) * 20 + col] = v;
    }
    // ---- stage recurrent patch (SAME-padded source) ----
    for (int i = threadIdx.x; i < 3 * 32 * 20; i += 256) {
        int row = i / (32 * 20);
        int r2  = i % (32 * 20);
        int ci  = r2 / 20;
        int col = r2 % 20;
        int gy = y0 + row, gx = x0 - 1 + col;
        float v = 0.f;
        if (col < 18 && gy < Ho && gx >= 0 && gx < Wo)
            v = hprev[(((size_t)b * Ho + gy) * Wo + gx) * 32 + ci];
        prc[(row * 32 + ci) * 20 + col] = v;
    }
    __syncthreads();

    float acc[4][4];
#pragma unroll
    for (int p = 0; p < 4; p++)
#pragma unroll
        for (int g = 0; g < 4; g++) acc[p][g] = 0.f;

    // ---- input convolution ----
#pragma unroll
    for (int ci = 0; ci < CIN; ci++) {
#pragma unroll
        for (int ky = 0; ky < 2; ky++) {
            float hw[6];
            const float* hp = &pin[((yr + ky) * CIN + ci) * 20 + cb];
            *(float4*)&hw[0] = *(const float4*)hp;
            *(float2*)&hw[4] = *(const float2*)(hp + 4);
#pragma unroll
            for (int kx = 0; kx < 3; kx++) {
                float4 w = *(const float4*)&Wt[((ci * 6 + ky * 3 + kx) * 32 + f) * 4];
#pragma unroll
                for (int p = 0; p < 4; p++) {
                    float hv = hw[p + kx];
                    acc[p][0] = fmaf(hv, w.x, acc[p][0]);
                    acc[p][1] = fmaf(hv, w.y, acc[p][1]);
                    acc[p][2] = fmaf(hv, w.z, acc[p][2]);
                    acc[p][3] = fmaf(hv, w.w, acc[p][3]);
                }
            }
        }
    }

    // ---- recurrent convolution ----
#pragma unroll 4
    for (int ci = 0; ci < 32; ci++) {
#pragma unroll
        for (int ky = 0; ky < 2; ky++) {
            float hw[6];
            const float* hp = &prc[((yr + ky) * 32 + ci) * 20 + cb];
            *(float4*)&hw[0] = *(const float4*)hp;
            *(float2*)&hw[4] = *(const float2*)(hp + 4);
#pragma unroll
            for (int kx = 0; kx < 3; kx++) {
                float4 w = *(const float4*)&Ut[((ci * 6 + ky * 3 + kx) * 32 + f) * 4];
#pragma unroll
                for (int p = 0; p < 4; p++) {
                    float hv = hw[p + kx];
                    acc[p][0] = fmaf(hv, w.x, acc[p][0]);
                    acc[p][1] = fmaf(hv, w.y, acc[p][1]);
                    acc[p][2] = fmaf(hv, w.z, acc[p][2]);
                    acc[p][3] = fmaf(hv, w.w, acc[p][3]);
                }
            }
        }
    }

    // ---- gates + state update ----
    if (y < Ho) {
        float bi = bias[f], bf = bias[32 + f], bc = bias[64 + f], bo = bias[96 + f];
#pragma unroll
        for (int p = 0; p < 4; p++) {
            int x = x0 + cb + p;
            if (x < Wo) {
                size_t o = (((size_t)b * Ho + y) * Wo + x) * 32 + f;
                float ig = hsig(acc[p][0] + bi);
                float fg = hsig(acc[p][1] + bf);
                float gg = fmaxf(acc[p][2] + bc, 0.f);
                float og = hsig(acc[p][3] + bo);
                float cn = fg * cst[o] + ig * gg;
                cst[o]   = cn;
                hnext[o] = og * fmaxf(cn, 0.f);
            }
        }
    }
}

// ---------------------------------------------------------------------------
// MaxPool(1,2,2) on h2_t + accumulate dense1 partial products into d1[B,10]
// Grid: (PH, B). Flat feature index of pooled elem: ((t*23+py)*22+px)*32+f
// ---------------------------------------------------------------------------
__global__ __launch_bounds__(256) void pool_dense(
    const float* __restrict__ h2, const float* __restrict__ Wd1,
    float* __restrict__ d1, int t)
{
    int b  = blockIdx.y;
    int py = blockIdx.x;
    float part[10];
#pragma unroll
    for (int j = 0; j < 10; j++) part[j] = 0.f;

    for (int e = threadIdx.x; e < PW * 32; e += 256) {
        int px = e >> 5, f = e & 31;
        size_t base = (((size_t)b * H2 + py * 2) * W2D + px * 2) * 32 + f;
        float m = fmaxf(fmaxf(h2[base], h2[base + 32]),
                        fmaxf(h2[base + W2D * 32], h2[base + W2D * 32 + 32]));
        size_t row = ((((size_t)t * PH + py) * PW + px) * 32 + f);
        const float* wr = Wd1 + row * 10;
#pragma unroll
        for (int j = 0; j < 10; j++) part[j] = fmaf(m, wr[j], part[j]);
    }

    __shared__ float red[10][4];
    int lane = threadIdx.x & 63, w = threadIdx.x >> 6;
#pragma unroll
    for (int j = 0; j < 10; j++) {
        float v = part[j];
        for (int off = 32; off > 0; off >>= 1) v += __shfl_down(v, off);
        if (lane == 0) red[j][w] = v;
    }
    __syncthreads();
    if (threadIdx.x < 10) {
        float s = red[threadIdx.x][0] + red[threadIdx.x][1] +
                  red[threadIdx.x][2] + red[threadIdx.x][3];
        atomicAdd(&d1[b * 10 + threadIdx.x], s);
    }
}

__global__ void final_dense(const float* __restrict__ d1, const float* __restrict__ bd1,
                            const float* __restrict__ Wd2, const float* __restrict__ bd2,
                            float* __restrict__ out)
{
    int b = threadIdx.x;
    if (b < B) {
        float s = bd2[0];
#pragma unroll
        for (int j = 0; j < 10; j++) s += (d1[b * 10 + j] + bd1[j]) * Wd2[j];
        out[b] = s;
    }
}

// ---------------------------------------------------------------------------
extern "C" void kernel_launch(void* const* d_in, const int* in_sizes, int n_in,
                              void* d_out, int out_size, void* d_ws, size_t ws_size,
                              hipStream_t stream)
{
    const float* x   = (const float*)d_in[0];
    const float* W1s = (const float*)d_in[1];
    const float* U1s = (const float*)d_in[2];
    const float* b1  = (const float*)d_in[3];
    const float* W2s = (const float*)d_in[4];
    const float* U2s = (const float*)d_in[5];
    const float* b2  = (const float*)d_in[6];
    const float* Wd1 = (const float*)d_in[7];
    const float* bd1 = (const float*)d_in[8];
    const float* Wd2 = (const float*)d_in[9];
    const float* bd2 = (const float*)d_in[10];
    float* out = (float*)d_out;

    const size_t H1SZ = (size_t)B * H1 * W1D * NF;  // 1,106,944
    const size_t H2SZ = (size_t)B * H2 * W2D * NF;  // 1,036,288

    float* ws  = (float*)d_ws;
    float* Wt1 = ws;                 // 2304
    float* Ut1 = Wt1 + 2304;         // 24576
    float* Wt2 = Ut1 + 24576;        // 24576
    float* Ut2 = Wt2 + 24576;        // 24576
    float* h1a = Ut2 + 24576;        // H1SZ
    float* c1  = h1a + H1SZ;         // H1SZ
    float* h2a = c1  + H1SZ;         // H2SZ
    float* c2  = h2a + H2SZ;         // H2SZ
    float* d1  = c2  + H2SZ;         // 160
    float* h1b = d1  + 160;          // H1SZ
    float* h2b = h1b + H1SZ;         // H2SZ

    // zero h1a, c1, h2a, c2, d1 (contiguous region)
    size_t zero_floats = 2 * H1SZ + 2 * H2SZ + 160;
    hipMemsetAsync(h1a, 0, zero_floats * sizeof(float), stream);

    transform_weights<<<297, 256, 0, stream>>>(W1s, U1s, W2s, U2s, Wt1, Ut1, Wt2, Ut2);

    for (int t = 0; t < T; t++) {
        float* h1p = (t & 1) ? h1b : h1a;
        float* h1n = (t & 1) ? h1a : h1b;
        float* h2p = (t & 1) ? h2b : h2a;
        float* h2n = (t & 1) ? h2a : h2b;

        // layer 1: input x[:,t], valid conv from 48x48x3 -> 47x46, recur on 47x46x32
        lstm_step<3><<<dim3(3, 24, B), 256, 0, stream>>>(
            x + (size_t)t * HIN * WIN * CINX, T * HIN * WIN * CINX, HIN, WIN,
            h1p, Wt1, Ut1, b1, c1, h1n, H1, W1D);

        // layer 2: input h1_t, valid conv 47x46x32 -> 46x44, recur on 46x44x32
        lstm_step<32><<<dim3(3, 23, B), 256, 0, stream>>>(
            h1n, (int)(H1SZ / B), H1, W1D,
            h2p, Wt2, Ut2, b2, c2, h2n, H2, W2D);

        // pool + dense1 accumulate
        pool_dense<<<dim3(PH, B), 256, 0, stream>>>(h2n, Wd1, d1, t);
    }

    final_dense<<<1, 64, 0, stream>>>(d1, bd1, Wd2, bd2, out);
}

// Round 2
// 506.912 us; speedup vs baseline: 2.8235x; 2.8235x over previous
//
#include <hip/hip_runtime.h>
#include <math.h>

// ---------------- problem constants ----------------
#define NB 16      // batch
#define TT 12      // timesteps
// layer 1: in x[48][48][3] -> out 47x46x32 ; layer 2: in 47x46x32 -> out 46x44x32
#define H1 47
#define W1D 46
#define H2 46
#define W2D 44

typedef short short8v __attribute__((ext_vector_type(8)));
typedef float floatx4 __attribute__((ext_vector_type(4)));

__device__ __forceinline__ short f2bf(float x) {
    unsigned u = __float_as_uint(x);
    u = (u + 0x7FFFu + ((u >> 16) & 1u)) >> 16;   // RNE
    return (short)u;
}
__device__ __forceinline__ float bf2f(short s) {
    return __uint_as_float(((unsigned)(unsigned short)s) << 16);
}
__device__ __forceinline__ float hsig(float z) {
    return fminf(fmaxf(0.2f * z + 0.5f, 0.f), 1.f);
}

// ---------------------------------------------------------------------------
// x fp32 -> bf16 (same layout [B][T][48][48][3])
// ---------------------------------------------------------------------------
__global__ __launch_bounds__(256) void convert_x(const float* __restrict__ x,
                                                 short* __restrict__ xbf, int n) {
    int i = blockIdx.x * 256 + threadIdx.x;
    if (i < n) xbf[i] = f2bf(x[i]);
}

// ---------------------------------------------------------------------------
// Weights -> MFMA B-fragment layout, bf16.
// Bt[layer] flat idx = ((c*2+fh)*4+g)*512 + j*32 + ci
//   column = g*32 + fh*16 + j ; k(within chunk) = ci
// Layer1: c=0 input conv (k = kk*3+cc, zero-padded 18->32), c=1..6 recur kk=c-1
// Layer2: c=0..5 input conv kk=c, c=6..11 recur kk=c-6
// ---------------------------------------------------------------------------
__global__ __launch_bounds__(256) void transform_w(
    const float* __restrict__ W1s, const float* __restrict__ U1s,
    const float* __restrict__ W2s, const float* __restrict__ U2s,
    short* __restrict__ Bt1, short* __restrict__ Bt2)
{
    int idx = blockIdx.x * 256 + threadIdx.x;       // 0..77823
    int layer2 = idx >= 28672;
    int i = layer2 ? idx - 28672 : idx;
    int ci = i & 31, j = (i >> 5) & 15, g = (i >> 9) & 3, fh = (i >> 11) & 1, c = i >> 12;
    int col = g * 32 + fh * 16 + j;
    float v = 0.f;
    if (!layer2) {
        if (c == 0) {
            if (ci < 18) { int kk = ci / 3, cc = ci - kk * 3; v = W1s[(kk * 3 + cc) * 128 + col]; }
        } else {
            v = U1s[((c - 1) * 32 + ci) * 128 + col];
        }
    } else {
        if (c < 6) v = W2s[(c * 32 + ci) * 128 + col];
        else       v = U2s[((c - 6) * 32 + ci) * 128 + col];
    }
    (layer2 ? Bt2 : Bt1)[i] = f2bf(v);
}

// ---------------------------------------------------------------------------
// One ConvLSTM timestep, implicit-GEMM via mfma_f32_16x16x32_bf16.
// Block 256 thr = 4 waves = (mhalf 0..1) x (fh 0..1). Block tile: 4 rows x 16 cols.
// Wave: M=32 (2 rows x 16 cols), N=64 (4 gates x 16 f-channels fh-half).
// K-loop: chunks of 32 = one kernel position (x conv: 1 padded im2col chunk).
// No barrier in K-loop; A-frags stream straight from global (coalesced 1KB/wave).
// ---------------------------------------------------------------------------
template<int LAYER>
__global__ __launch_bounds__(256) void lstm_mfma(
    const short* __restrict__ xin,     // L1: xbf + t*6912 ; L2: h1 current (bf16)
    const short* __restrict__ hprev,   // previous h of this layer (bf16, slacked)
    const short* __restrict__ Bt,
    const float* __restrict__ bias,    // [128]
    float* __restrict__ cst,           // fp32 cell state
    short* __restrict__ hnext)         // bf16 h output
{
    constexpr int Ho   = (LAYER == 1) ? H1 : H2;
    constexpr int Wo   = (LAYER == 1) ? W1D : W2D;
    constexpr int NCH  = (LAYER == 1) ? 7 : 12;
    constexpr int REC0 = (LAYER == 1) ? 1 : 6;
    constexpr int IW   = (LAYER == 1) ? 48 : W1D;               // input-conv src width
    constexpr int IBS  = (LAYER == 1) ? (TT * 48 * 48 * 3) : (H1 * W1D * 32);
    constexpr int HBS  = Ho * Wo * 32;

    const int tid  = threadIdx.x;
    const int lane = tid & 63;
    const int w    = tid >> 6;
    const int mhalf = w >> 1, fh = w & 1;
    const int tx = lane & 15, q = lane >> 4;
    const int b = blockIdx.z, y0 = blockIdx.y * 4, x0 = blockIdx.x * 16;

    __shared__ short xim[64 * 40];
    if (LAYER == 1) {
        // padded im2col of x for chunk 0: rows m=0..63 (4x16 tile), k=kk*3+cc (18, pad 32)
        for (int i = tid; i < 64 * 32; i += 256) {
            int m = i >> 5, k = i & 31;
            int tym = m >> 4, txm = m & 15;
            short v = 0;
            if (k < 18) {
                int kk = k / 3, cc = k - kk * 3;
                int ky = (kk >= 3) ? 1 : 0, kx = kk - ky * 3;
                int ys = y0 + tym + ky; if (ys > 47) ys = 47;   // clamp (invalid-m rows)
                int xs = x0 + txm + kx; if (xs > 47) xs = 47;
                v = xin[b * IBS + (ys * 48 + xs) * 3 + cc];
            }
            xim[m * 40 + k] = v;
        }
        __syncthreads();
    }

    int base_in[2], base_rc[2];
    bool okY[2][2];
#pragma unroll
    for (int a = 0; a < 2; ++a) {
        int ty = mhalf * 2 + a;
        base_in[a] = b * IBS + ((y0 + ty) * IW + (x0 + tx)) * 32 + q * 8;   // L2 only
        base_rc[a] = b * HBS + ((y0 + ty) * Wo + (x0 + tx - 1)) * 32 + q * 8;
        okY[a][0] = (y0 + ty) < Ho;
        okY[a][1] = (y0 + ty + 1) < Ho;
    }
    bool okX[3];
#pragma unroll
    for (int kx = 0; kx < 3; ++kx)
        okX[kx] = (unsigned)(x0 + tx + kx - 1) < (unsigned)Wo;

    const short* Btl = Bt + fh * 2048 + tx * 32 + q * 8;

    floatx4 acc[2][4] = {};
    const short8v z8 = (short8v)0;

#pragma unroll
    for (int c = 0; c < NCH; ++c) {
        short8v bf4[4], af[2];
#pragma unroll
        for (int g = 0; g < 4; ++g)
            bf4[g] = *(const short8v*)(Btl + c * 4096 + g * 512);

        if (LAYER == 1 && c == 0) {
#pragma unroll
            for (int a = 0; a < 2; ++a)
                af[a] = *(const short8v*)&xim[((mhalf * 2 + a) * 16 + tx) * 40 + q * 8];
        } else if (LAYER == 2 && c < REC0) {
            int ky = (c >= 3) ? 1 : 0, kx = c - ky * 3;
#pragma unroll
            for (int a = 0; a < 2; ++a)
                af[a] = *(const short8v*)(xin + base_in[a] + (ky * IW + kx) * 32);
        } else {
            int kk = c - REC0;
            int ky = (kk >= 3) ? 1 : 0, kx = kk - ky * 3;
#pragma unroll
            for (int a = 0; a < 2; ++a) {
                short8v v = *(const short8v*)(hprev + base_rc[a] + (ky * Wo + kx) * 32);
                af[a] = (okY[a][ky] && okX[kx]) ? v : z8;
            }
        }
#pragma unroll
        for (int a = 0; a < 2; ++a)
#pragma unroll
            for (int g = 0; g < 4; ++g)
                acc[a][g] = __builtin_amdgcn_mfma_f32_16x16x32_bf16(af[a], bf4[g], acc[a][g], 0, 0, 0);
    }

    // ---- fused LSTM epilogue (C layout: col=lane&15 -> f, row=q*4+r -> x) ----
    const int f = fh * 16 + tx;
    const float bi = bias[f], bfv = bias[32 + f], bcv = bias[64 + f], bov = bias[96 + f];
#pragma unroll
    for (int a = 0; a < 2; ++a) {
        int y = y0 + mhalf * 2 + a;
        if (y < Ho) {
#pragma unroll
            for (int r = 0; r < 4; ++r) {
                int xe = x0 + q * 4 + r;
                if (xe < Wo) {
                    int o = b * HBS + (y * Wo + xe) * 32 + f;
                    float ig = hsig(acc[a][0][r] + bi);
                    float fg = hsig(acc[a][1][r] + bfv);
                    float gg = fmaxf(acc[a][2][r] + bcv, 0.f);
                    float og = hsig(acc[a][3][r] + bov);
                    float cn = fg * cst[o] + ig * gg;
                    cst[o] = cn;
                    hnext[o] = f2bf(og * fmaxf(cn, 0.f));
                }
            }
        }
    }
}

// ---------------------------------------------------------------------------
// MaxPool(1,2,2) of h2_t (bf16) -> pooled buffer p[b][k], k=((t*23+py)*22+px)*32+f
// (max of bf16 values is exactly representable -> no extra rounding loss)
// ---------------------------------------------------------------------------
__global__ __launch_bounds__(256) void pool_kernel(
    const short* __restrict__ h2, short* __restrict__ p, int t)
{
    int b = blockIdx.y, py = blockIdx.x;
    for (int e = threadIdx.x; e < 22 * 32; e += 256) {
        int px = e >> 5, f = e & 31;
        int base = ((b * H2 + py * 2) * W2D + px * 2) * 32 + f;
        float m0 = bf2f(h2[base]),            m1 = bf2f(h2[base + 32]);
        float m2 = bf2f(h2[base + W2D * 32]), m3 = bf2f(h2[base + W2D * 32 + 32]);
        float m = fmaxf(fmaxf(m0, m1), fmaxf(m2, m3));
        p[(size_t)b * 194304 + ((t * 23 + py) * 22 + px) * 32 + f] = f2bf(m);
    }
}

// ---------------------------------------------------------------------------
// d1[b][j] += sum_k p[b][k] * Wd1[k][j]   (K=194304 split 64 ways)
// ---------------------------------------------------------------------------
__global__ __launch_bounds__(256) void gemv_kernel(
    const short* __restrict__ p, const float* __restrict__ Wd1, float* __restrict__ d1)
{
    int b = blockIdx.y;
    int k0 = blockIdx.x * 3036;                     // 194304 / 64
    float part[10];
#pragma unroll
    for (int j = 0; j < 10; j++) part[j] = 0.f;
    for (int k = k0 + threadIdx.x; k < k0 + 3036; k += 256) {
        float m = bf2f(p[(size_t)b * 194304 + k]);
        const float* wr = Wd1 + (size_t)k * 10;
#pragma unroll
        for (int j = 0; j < 10; j++) part[j] = fmaf(m, wr[j], part[j]);
    }
    __shared__ float red[10][4];
    int lane = threadIdx.x & 63, wv = threadIdx.x >> 6;
#pragma unroll
    for (int j = 0; j < 10; j++) {
        float v = part[j];
        for (int off = 32; off > 0; off >>= 1) v += __shfl_down(v, off);
        if (lane == 0) red[j][wv] = v;
    }
    __syncthreads();
    if (threadIdx.x < 10) {
        float s = red[threadIdx.x][0] + red[threadIdx.x][1] +
                  red[threadIdx.x][2] + red[threadIdx.x][3];
        atomicAdd(&d1[b * 10 + threadIdx.x], s);
    }
}

__global__ void final_dense(const float* __restrict__ d1, const float* __restrict__ bd1,
                            const float* __restrict__ Wd2, const float* __restrict__ bd2,
                            float* __restrict__ out)
{
    int b = threadIdx.x;
    if (b < NB) {
        float s = bd2[0];
#pragma unroll
        for (int j = 0; j < 10; j++) s += (d1[b * 10 + j] + bd1[j]) * Wd2[j];
        out[b] = s;
    }
}

// ---------------------------------------------------------------------------
extern "C" void kernel_launch(void* const* d_in, const int* in_sizes, int n_in,
                              void* d_out, int out_size, void* d_ws, size_t ws_size,
                              hipStream_t stream)
{
    const float* x   = (const float*)d_in[0];
    const float* W1s = (const float*)d_in[1];
    const float* U1s = (const float*)d_in[2];
    const float* b1  = (const float*)d_in[3];
    const float* W2s = (const float*)d_in[4];
    const float* U2s = (const float*)d_in[5];
    const float* b2  = (const float*)d_in[6];
    const float* Wd1 = (const float*)d_in[7];
    const float* bd1 = (const float*)d_in[8];
    const float* Wd2 = (const float*)d_in[9];
    const float* bd2 = (const float*)d_in[10];
    float* out = (float*)d_out;

    const int H1N = NB * H1 * W1D * 32;   // 1106944
    const int H2N = NB * H2 * W2D * 32;   // 1036288
    const int SLF = 32, SLB = 8192;       // front/back slack (elems) for OOB-safe loads
    const int SPAN1 = SLF + H1N + SLB;    // 1115168
    const int SPAN2 = SLF + H2N + SLB;    // 1044512

    short* Bt1 = (short*)d_ws;            // 28672
    short* Bt2 = Bt1 + 28672;             // 49152
    short* xbf = Bt2 + 49152;             // 1327104
    short* p   = xbf + 1327104;           // 16*194304 = 3108864
    short* zr  = p + 3108864;             // ---- zero region start ----
    short* h1a = zr + SLF;
    short* h1b = zr + SPAN1 + SLF;
    short* h2a = zr + 2 * SPAN1 + SLF;
    short* h2b = zr + 2 * SPAN1 + SPAN2 + SLF;
    float* c1  = (float*)(zr + 2 * SPAN1 + 2 * SPAN2);
    float* c2  = c1 + H1N;
    float* d1  = c2 + H2N;                // 160 floats
    size_t zero_bytes = (size_t)(2 * SPAN1 + 2 * SPAN2) * 2 + (size_t)(H1N + H2N + 160) * 4;

    hipMemsetAsync(zr, 0, zero_bytes, stream);
    convert_x<<<(1327104 + 255) / 256, 256, 0, stream>>>(x, xbf, 1327104);
    transform_w<<<304, 256, 0, stream>>>(W1s, U1s, W2s, U2s, Bt1, Bt2);

    for (int t = 0; t < TT; t++) {
        short* h1p = (t & 1) ? h1b : h1a;
        short* h1n = (t & 1) ? h1a : h1b;
        short* h2p = (t & 1) ? h2b : h2a;
        short* h2n = (t & 1) ? h2a : h2b;

        lstm_mfma<1><<<dim3(3, 12, NB), 256, 0, stream>>>(
            xbf + t * 48 * 48 * 3, h1p, Bt1, b1, c1, h1n);
        lstm_mfma<2><<<dim3(3, 12, NB), 256, 0, stream>>>(
            h1n, h2p, Bt2, b2, c2, h2n);
        pool_kernel<<<dim3(23, NB), 256, 0, stream>>>(h2n, p, t);
    }

    gemv_kernel<<<dim3(64, NB), 256, 0, stream>>>(p, Wd1, d1);
    final_dense<<<1, 64, 0, stream>>>(d1, bd1, Wd2, bd2, out);
}

// Round 3
// 379.990 us; speedup vs baseline: 3.7666x; 1.3340x over previous
//
#include <hip/hip_runtime.h>
#include <math.h>

// ---------------- problem constants ----------------
#define NB 16
#define TT 12
#define H1 47
#define W1D 46
#define H2 46
#define W2D 44

typedef short short8v __attribute__((ext_vector_type(8)));
typedef float floatx4 __attribute__((ext_vector_type(4)));

__device__ __forceinline__ short f2bf(float x) {
    unsigned u = __float_as_uint(x);
    u = (u + 0x7FFFu + ((u >> 16) & 1u)) >> 16;   // RNE
    return (short)u;
}
__device__ __forceinline__ float bf2f(short s) {
    return __uint_as_float(((unsigned)(unsigned short)s) << 16);
}
__device__ __forceinline__ float hsig(float z) {
    return fminf(fmaxf(0.2f * z + 0.5f, 0.f), 1.f);
}

// ---------------------------------------------------------------------------
__global__ __launch_bounds__(256) void convert_x(const float* __restrict__ x,
                                                 short* __restrict__ xbf, int n) {
    int i = blockIdx.x * 256 + threadIdx.x;
    if (i < n) xbf[i] = f2bf(x[i]);
}

// ---------------------------------------------------------------------------
// Weights -> MFMA B-fragment layout, bf16 (same as R2).
// flat idx = ((c*2+fh)*4+g)*512 + j*32 + ci ; column = g*32+fh*16+j, k = ci
// ---------------------------------------------------------------------------
__global__ __launch_bounds__(256) void transform_w(
    const float* __restrict__ W1s, const float* __restrict__ U1s,
    const float* __restrict__ W2s, const float* __restrict__ U2s,
    short* __restrict__ Bt1, short* __restrict__ Bt2)
{
    int idx = blockIdx.x * 256 + threadIdx.x;       // 0..77823
    int layer2 = idx >= 28672;
    int i = layer2 ? idx - 28672 : idx;
    int ci = i & 31, j = (i >> 5) & 15, g = (i >> 9) & 3, fh = (i >> 11) & 1, c = i >> 12;
    int col = g * 32 + fh * 16 + j;
    float v = 0.f;
    if (!layer2) {
        if (c == 0) {
            if (ci < 18) { int kk = ci / 3, cc = ci - kk * 3; v = W1s[(kk * 3 + cc) * 128 + col]; }
        } else {
            v = U1s[((c - 1) * 32 + ci) * 128 + col];
        }
    } else {
        if (c < 6) v = W2s[(c * 32 + ci) * 128 + col];
        else       v = U2s[((c - 6) * 32 + ci) * 128 + col];
    }
    (layer2 ? Bt2 : Bt1)[i] = f2bf(v);
}

// ---------------------------------------------------------------------------
// One ConvLSTM timestep body. Block tile 8 rows x 16 cols (M=128), N=128.
// 4 waves = (mhalf 0..1) x (fh 0..1); wave M=64 (4 A-frags), N=64.
// 16 MFMAs per k-chunk per wave; A/B stream from global (L1/L2-hit), no
// barrier in the K-loop. LAYER==2 fuses MaxPool(2,2) into the epilogue.
// ---------------------------------------------------------------------------
template<int LAYER>
__device__ __forceinline__ void step_body(
    const short* __restrict__ xin,     // L1: xbf + t*6912 ; L2: h1[t'] (bf16)
    const short* __restrict__ hprev,   // recurrent h (bf16, slacked)
    const short* __restrict__ Bt,
    const float* __restrict__ bias,
    float* __restrict__ cst,
    short* __restrict__ hnext,
    short* __restrict__ pool, int t2, int b, short* xim)
{
    constexpr int Ho   = (LAYER == 1) ? H1 : H2;
    constexpr int Wo   = (LAYER == 1) ? W1D : W2D;
    constexpr int NCH  = (LAYER == 1) ? 7 : 12;
    constexpr int REC0 = (LAYER == 1) ? 1 : 6;
    constexpr int IW   = (LAYER == 1) ? 48 : W1D;
    constexpr int IBS  = (LAYER == 1) ? (TT * 48 * 48 * 3) : (H1 * W1D * 32);
    constexpr int HBS  = Ho * Wo * 32;

    const int tid = threadIdx.x;
    const int lane = tid & 63, w = tid >> 6;
    const int mhalf = w >> 1, fh = w & 1;
    const int tx = lane & 15, q = lane >> 4;
    const int y0 = blockIdx.y * 8, x0 = blockIdx.x * 16;

    if (LAYER == 1) {
        // padded im2col chunk of x: m=0..127 (8x16 tile), k=kk*3+cc (18 -> pad 32)
        for (int i = tid; i < 128 * 32; i += 256) {
            int m = i >> 5, k = i & 31;
            short v = 0;
            if (k < 18) {
                int kk = k / 3, cc = k - kk * 3;
                int ky = (kk >= 3) ? 1 : 0, kx = kk - ky * 3;
                int ys = y0 + (m >> 4) + ky; if (ys > 47) ys = 47;
                int xs = x0 + (m & 15) + kx; if (xs > 47) xs = 47;
                v = xin[b * IBS + (ys * 48 + xs) * 3 + cc];
            }
            xim[m * 40 + k] = v;
        }
        __syncthreads();
    }

    int base_in[4], base_rc[4];
    bool okYr[4][2];
#pragma unroll
    for (int a = 0; a < 4; ++a) {
        int y = y0 + mhalf * 4 + a;
        base_in[a] = b * IBS + (y * IW + (x0 + tx)) * 32 + q * 8;
        base_rc[a] = b * HBS + (y * Wo + (x0 + tx - 1)) * 32 + q * 8;
        okYr[a][0] = y < Ho;
        okYr[a][1] = (y + 1) < Ho;
    }
    bool okX[3];
#pragma unroll
    for (int kx = 0; kx < 3; ++kx)
        okX[kx] = (unsigned)(x0 + tx - 1 + kx) < (unsigned)Wo;

    const short* Btl = Bt + fh * 2048 + tx * 32 + q * 8;
    floatx4 acc[4][4] = {};   // [a][gate]
    const short8v z8 = (short8v)0;

#pragma unroll
    for (int c = 0; c < NCH; ++c) {
        short8v bf4[4], af[4];
#pragma unroll
        for (int g = 0; g < 4; ++g)
            bf4[g] = *(const short8v*)(Btl + c * 4096 + g * 512);

        if (LAYER == 1 && c == 0) {
#pragma unroll
            for (int a = 0; a < 4; ++a)
                af[a] = *(const short8v*)&xim[((mhalf * 4 + a) * 16 + tx) * 40 + q * 8];
        } else if (LAYER == 2 && c < REC0) {
            int ky = (c >= 3) ? 1 : 0, kx = c - ky * 3;
#pragma unroll
            for (int a = 0; a < 4; ++a)
                af[a] = *(const short8v*)(xin + base_in[a] + (ky * IW + kx) * 32);
        } else {
            int kk = c - REC0;
            int ky = (kk >= 3) ? 1 : 0, kx = kk - ky * 3;
#pragma unroll
            for (int a = 0; a < 4; ++a) {
                short8v v = *(const short8v*)(hprev + base_rc[a] + (ky * Wo + kx) * 32);
                af[a] = (okYr[a][ky] && okX[kx]) ? v : z8;
            }
        }
#pragma unroll
        for (int a = 0; a < 4; ++a)
#pragma unroll
            for (int g = 0; g < 4; ++g)
                acc[a][g] = __builtin_amdgcn_mfma_f32_16x16x32_bf16(af[a], bf4[g], acc[a][g], 0, 0, 0);
    }

    // ---- fused LSTM epilogue (C layout: col=tx -> f, row=q*4+r -> x) ----
    const int f = fh * 16 + tx;
    const float bi = bias[f], bfv = bias[32 + f], bcv = bias[64 + f], bov = bias[96 + f];
    float hv[4][4];
#pragma unroll
    for (int a = 0; a < 4; ++a) {
        int y = y0 + mhalf * 4 + a;
        bool yok = y < Ho;
#pragma unroll
        for (int r = 0; r < 4; ++r) {
            int xe = x0 + q * 4 + r;
            float hn = 0.f;
            if (yok && xe < Wo) {
                int o = b * HBS + (y * Wo + xe) * 32 + f;
                float ig = hsig(acc[a][0][r] + bi);
                float fg = hsig(acc[a][1][r] + bfv);
                float gg = fmaxf(acc[a][2][r] + bcv, 0.f);
                float og = hsig(acc[a][3][r] + bov);
                float cn = fg * cst[o] + ig * gg;
                cst[o] = cn;
                short hb = f2bf(og * fmaxf(cn, 0.f));
                hnext[o] = hb;
                hn = bf2f(hb);
            }
            hv[a][r] = hn;
        }
    }

    if (LAYER == 2) {
        // MaxPool(2,2): y-pairs are a-pairs, x-pairs are r-pairs (thread-local)
#pragma unroll
        for (int ap = 0; ap < 2; ++ap) {
            int py = y0 / 2 + mhalf * 2 + ap;
#pragma unroll
            for (int rp = 0; rp < 2; ++rp) {
                int px = x0 / 2 + q * 2 + rp;
                if (py < 23 && px < 22) {
                    float m = fmaxf(fmaxf(hv[2 * ap][2 * rp],     hv[2 * ap][2 * rp + 1]),
                                    fmaxf(hv[2 * ap + 1][2 * rp], hv[2 * ap + 1][2 * rp + 1]));
                    pool[(size_t)b * 194304 + ((t2 * 23 + py) * 22 + px) * 32 + f] = f2bf(m);
                }
            }
        }
    }
}

// ---------------------------------------------------------------------------
// Fused pipeline step: blocks z<16 run L1(t=s), z>=16 run L2(t=s-1)+pool.
// ---------------------------------------------------------------------------
__global__ __launch_bounds__(256, 2) void fused_step(
    const short* __restrict__ xt,
    const short* __restrict__ h1r, short* __restrict__ h1w,
    const short* __restrict__ h2r, short* __restrict__ h2w,
    const short* __restrict__ Bt1, const short* __restrict__ Bt2,
    const float* __restrict__ b1, const float* __restrict__ b2,
    float* __restrict__ c1, float* __restrict__ c2,
    short* __restrict__ pool, int t2, int do1, int do2)
{
    __shared__ short xim[128 * 40];
    int z = blockIdx.z, b = z & 15, layer = z >> 4;
    if (layer == 0) {
        if (!do1) return;
        step_body<1>(xt, h1r, Bt1, b1, c1, h1w, nullptr, 0, b, xim);
    } else {
        if (!do2) return;
        step_body<2>(h1r, h2r, Bt2, b2, c2, h2w, pool, t2, b, xim);
    }
}

// ---------------------------------------------------------------------------
// d1[b][j] += sum_k p[b][k]*Wd1[k][j]; block handles 4 batches (Wd1 read 4x not 16x)
// ---------------------------------------------------------------------------
__global__ __launch_bounds__(256) void gemv_kernel(
    const short* __restrict__ p, const float* __restrict__ Wd1, float* __restrict__ d1)
{
    int by = blockIdx.y;                 // batch group: 4*by .. 4*by+3
    int k0 = blockIdx.x * 3036;          // 194304 / 64
    float part[4][10];
#pragma unroll
    for (int bb = 0; bb < 4; bb++)
#pragma unroll
        for (int j = 0; j < 10; j++) part[bb][j] = 0.f;

    for (int k = k0 + threadIdx.x; k < k0 + 3036; k += 256) {
        const float* wr = Wd1 + (size_t)k * 10;
        float wv[10];
#pragma unroll
        for (int j = 0; j < 10; j++) wv[j] = wr[j];
#pragma unroll
        for (int bb = 0; bb < 4; bb++) {
            float m = bf2f(p[(size_t)(by * 4 + bb) * 194304 + k]);
#pragma unroll
            for (int j = 0; j < 10; j++) part[bb][j] = fmaf(m, wv[j], part[bb][j]);
        }
    }
    __shared__ float red[4][10][4];
    int lane = threadIdx.x & 63, wv2 = threadIdx.x >> 6;
#pragma unroll
    for (int bb = 0; bb < 4; bb++)
#pragma unroll
        for (int j = 0; j < 10; j++) {
            float v = part[bb][j];
            for (int off = 32; off > 0; off >>= 1) v += __shfl_down(v, off);
            if (lane == 0) red[bb][j][wv2] = v;
        }
    __syncthreads();
    if (threadIdx.x < 40) {
        int bb = threadIdx.x / 10, j = threadIdx.x % 10;
        float s = red[bb][j][0] + red[bb][j][1] + red[bb][j][2] + red[bb][j][3];
        atomicAdd(&d1[(by * 4 + bb) * 10 + j], s);
    }
}

__global__ void final_dense(const float* __restrict__ d1, const float* __restrict__ bd1,
                            const float* __restrict__ Wd2, const float* __restrict__ bd2,
                            float* __restrict__ out)
{
    int b = threadIdx.x;
    if (b < NB) {
        float s = bd2[0];
#pragma unroll
        for (int j = 0; j < 10; j++) s += (d1[b * 10 + j] + bd1[j]) * Wd2[j];
        out[b] = s;
    }
}

// ---------------------------------------------------------------------------
extern "C" void kernel_launch(void* const* d_in, const int* in_sizes, int n_in,
                              void* d_out, int out_size, void* d_ws, size_t ws_size,
                              hipStream_t stream)
{
    const float* x   = (const float*)d_in[0];
    const float* W1s = (const float*)d_in[1];
    const float* U1s = (const float*)d_in[2];
    const float* b1  = (const float*)d_in[3];
    const float* W2s = (const float*)d_in[4];
    const float* U2s = (const float*)d_in[5];
    const float* b2  = (const float*)d_in[6];
    const float* Wd1 = (const float*)d_in[7];
    const float* bd1 = (const float*)d_in[8];
    const float* Wd2 = (const float*)d_in[9];
    const float* bd2 = (const float*)d_in[10];
    float* out = (float*)d_out;

    const int H1N = NB * H1 * W1D * 32;   // 1106944
    const int H2N = NB * H2 * W2D * 32;   // 1036288
    const int SLF = 32, SLB = 8192;
    const int SPAN1 = SLF + H1N + SLB;
    const int SPAN2 = SLF + H2N + SLB;

    short* Bt1 = (short*)d_ws;            // 28672
    short* Bt2 = Bt1 + 28672;             // 49152
    short* xbf = Bt2 + 49152;             // 1327104
    short* p   = xbf + 1327104;           // 3108864
    short* zr  = p + 3108864;             // ---- zero region ----
    short* h1a = zr + SLF;
    short* h1b = zr + SPAN1 + SLF;
    short* h2a = zr + 2 * SPAN1 + SLF;
    short* h2b = zr + 2 * SPAN1 + SPAN2 + SLF;
    float* c1  = (float*)(zr + 2 * SPAN1 + 2 * SPAN2);
    float* c2  = c1 + H1N;
    float* d1  = c2 + H2N;
    size_t zero_bytes = (size_t)(2 * SPAN1 + 2 * SPAN2) * 2 + (size_t)(H1N + H2N + 160) * 4;

    hipMemsetAsync(zr, 0, zero_bytes, stream);
    convert_x<<<(1327104 + 255) / 256, 256, 0, stream>>>(x, xbf, 1327104);
    transform_w<<<304, 256, 0, stream>>>(W1s, U1s, W2s, U2s, Bt1, Bt2);

    // software pipeline: kernel s runs L1(t=s) and L2(t=s-1)+pool
    for (int s = 0; s <= TT; s++) {
        const short* xt  = xbf + (s < TT ? s : 0) * 6912;
        short*       h1w = (s & 1) ? h1b : h1a;
        const short* h1r = (s & 1) ? h1a : h1b;
        short*       h2w = (s & 1) ? h2a : h2b;   // buf2[(s-1)%2]
        const short* h2r = (s & 1) ? h2b : h2a;   // buf2[(s-2)%2]
        fused_step<<<dim3(3, 6, 32), 256, 0, stream>>>(
            xt, h1r, h1w, h2r, h2w, Bt1, Bt2, b1, b2, c1, c2,
            p, s - 1, (int)(s < TT), (int)(s >= 1));
    }

    gemv_kernel<<<dim3(64, 4), 256, 0, stream>>>(p, Wd1, d1);
    final_dense<<<1, 64, 0, stream>>>(d1, bd1, Wd2, bd2, out);
}